// Round 6
// baseline (342.892 us; speedup 1.0000x reference)
//
#include <hip/hip_runtime.h>

// ---------------------------------------------------------------------------
// BiasedAttention fused pipeline (MI355X / gfx950) — R6
//   GEMMs -> 256x256 8-phase template (BK=64, 8 waves 2Mx4N, 128KB LDS dbuf,
//   per-quadrant phases, counted vmcnt(4) once per K-tile, XOR chunk swizzle
//   both-sides, setprio, XCD swizzle). attn/LN/transposes unchanged from R5.
// Workspace layout (bytes):
//   xn      bf16  8192*1024*2  = 16777216   @ 0
//   wqkv_t  bf16  3072*1024*2  =  6291456   @ 16777216
//   wout_t  bf16  1024*1024*2  =  2097152   @ 23068672
//   qkv     bf16  8192*3072*2  = 50331648   @ 25165824
//   aout    bf16  8192*1024*2  = 16777216   @ 75497472
// ---------------------------------------------------------------------------

#define DIM    1024
#define HEADS  16
#define DHEAD  64
#define INNER  1024
#define SEQ    1024
#define BATCH  8
#define QKV3   3072

typedef __bf16 bf16x8 __attribute__((ext_vector_type(8)));
typedef float f32x4 __attribute__((ext_vector_type(4)));
typedef unsigned short u16x8 __attribute__((ext_vector_type(8)));
typedef unsigned short u16x4 __attribute__((ext_vector_type(4)));

typedef __attribute__((address_space(1))) const unsigned int as1_uint;
typedef __attribute__((address_space(3))) unsigned int as3_uint;

static __device__ inline unsigned short f2bf(float f) {
  unsigned int u = __float_as_uint(f);
  u = (u + 0x7FFFu + ((u >> 16) & 1u)) >> 16;  // RNE
  return (unsigned short)u;
}
static __device__ inline unsigned short f2bf_fast(float f) {
  __bf16 h = (__bf16)f;
  return __builtin_bit_cast(unsigned short, h);
}

// ---------------------------------------------------------------------------
// 1. LayerNorm fp32 -> bf16  (unchanged)
// ---------------------------------------------------------------------------
__global__ __launch_bounds__(256) void ln_bf16_kernel(
    const float* __restrict__ x, const float* __restrict__ gamma,
    const float* __restrict__ beta, unsigned short* __restrict__ xn) {
  int row = blockIdx.x;
  int tid = threadIdx.x;
  const float4* xr = reinterpret_cast<const float4*>(x + (size_t)row * DIM);
  float4 v = xr[tid];
  float s = v.x + v.y + v.z + v.w;
  float s2 = v.x * v.x + v.y * v.y + v.z * v.z + v.w * v.w;
#pragma unroll
  for (int m = 32; m; m >>= 1) {
    s += __shfl_xor(s, m, 64);
    s2 += __shfl_xor(s2, m, 64);
  }
  __shared__ float red[2][4];
  int wid = tid >> 6, lane = tid & 63;
  if (lane == 0) { red[0][wid] = s; red[1][wid] = s2; }
  __syncthreads();
  s = red[0][0] + red[0][1] + red[0][2] + red[0][3];
  s2 = red[1][0] + red[1][1] + red[1][2] + red[1][3];
  float mu = s * (1.0f / DIM);
  float var = s2 * (1.0f / DIM) - mu * mu;
  float rstd = rsqrtf(var + 1e-5f);
  float4 g = reinterpret_cast<const float4*>(gamma)[tid];
  float4 b = reinterpret_cast<const float4*>(beta)[tid];
  u16x4 o;
  o[0] = f2bf((v.x - mu) * rstd * g.x + b.x);
  o[1] = f2bf((v.y - mu) * rstd * g.y + b.y);
  o[2] = f2bf((v.z - mu) * rstd * g.z + b.z);
  o[3] = f2bf((v.w - mu) * rstd * g.w + b.w);
  *reinterpret_cast<u16x4*>(xn + (size_t)row * DIM + tid * 4) = o;
}

// ---------------------------------------------------------------------------
// 2. Transpose + fp32->bf16  (unchanged)
// ---------------------------------------------------------------------------
__global__ __launch_bounds__(256) void transpose_cvt(
    const float* __restrict__ W, unsigned short* __restrict__ Wt, int R, int C,
    int scale_rows) {
  __shared__ float tb[32][33];
  int c0 = blockIdx.x * 32, r0 = blockIdx.y * 32;
  int tx = threadIdx.x, ty = threadIdx.y;  // (32, 8)
#pragma unroll
  for (int i = 0; i < 4; ++i)
    tb[ty + i * 8][tx] = W[(size_t)(r0 + ty + i * 8) * C + c0 + tx];
  __syncthreads();
#pragma unroll
  for (int i = 0; i < 4; ++i) {
    int orow = c0 + ty + i * 8;
    float v = tb[tx][ty + i * 8];
    if (orow < scale_rows) v *= 0.125f;
    Wt[(size_t)orow * R + r0 + tx] = f2bf(v);
  }
}

// ---------------------------------------------------------------------------
// 3. GEMM 256x256 8-phase.  C[M,N] = A[M,K] @ Bt[N,K]^T (bf16, fp32 acc).
//    8 waves 2Mx4N; per-wave C = 128x64 (8 M-frags x 4 N-frags).
//    LDS: As/Bs [2][256][64] linear rows (128B), XOR chunk swizzle
//    (chunk ^= row&7) applied on global SOURCE (stage) and ds_read addr.
//    Per K-tile t (buf cur=t&1), 4 quadrant phases:
//      p0: read A{m0}+B{n0}, stage A{m1}(t+1)->nxt, MFMA mi0-3 x ni0-1
//      p1: read B{n1},       stage B{n1}(t+1)->nxt, MFMA mi0-3 x ni2-3
//      p2: read A{m1},       stage A{m0}(t+2)->cur, MFMA mi4-7 x ni0-1
//      p3:                   stage B{n0}(t+2)->cur, MFMA mi4-7 x ni2-3,
//          vmcnt(4) (tile t+1 proven landed; t+2's 4 loads in flight)
//    Region deaths: A{m0},B{n0} die at p0's end barrier; B{n1} at p1; A{m1}
//    at p2 -> every stage lands >=1 barrier after its region's last reader.
//    A-half rows: {mh*64+[0,64)} u {mh*64+128+[0,64)}; B-half rows:
//    {64k+nh*32+[0,32), k=0..3} — staged as 16 wave-chunks of 8 rows.
// ---------------------------------------------------------------------------
template <bool F32OUT>
__global__ __launch_bounds__(512, 2) void gemm8(
    const unsigned short* __restrict__ A, const unsigned short* __restrict__ Bt,
    void* __restrict__ Cout, int M, int N, int K) {
  __shared__ unsigned short As[2][256 * 64];
  __shared__ unsigned short Bs[2][256 * 64];
  const int nb = N >> 8;
  const int nwg = (M >> 8) * nb;
  const int cpx = nwg >> 3;
  int phys = blockIdx.x;
  int swz = (phys & 7) * cpx + (phys >> 3);  // bijective, nwg%8==0
  int bm = swz / nb, bn = swz % nb;
  int tid = threadIdx.x, wid = tid >> 6, lane = tid & 63;
  int wr = wid >> 2, wc = wid & 3;
  int lg = lane >> 4, lr = lane & 15;
  const unsigned short* Ablk = A + (size_t)(bm * 256) * K;
  const unsigned short* Bblk = Bt + (size_t)(bn * 256) * K;
  const int NT = K >> 6;

  int srow8 = lane >> 3;  // staging: row within 8-row wave chunk
  int schk = lane & 7;    // staging: 16B chunk in row
  int axr = lr & 7;       // read-side XOR (row&7 == lr&7 at all frag rows)

#define G_STAGE_A(BUF, MH, KT)                                                 \
  {                                                                            \
    _Pragma("unroll") for (int i = 0; i < 2; ++i) {                            \
      int rb = (MH) * 64 + i * 128 + (wid << 3);                               \
      int r = rb + srow8;                                                      \
      __builtin_amdgcn_global_load_lds(                                        \
          (as1_uint*)(Ablk + (size_t)r * K + (KT) * 64 +                       \
                      ((schk ^ (r & 7)) << 3)),                                \
          (as3_uint*)(&As[BUF][rb * 64]), 16, 0, 0);                           \
    }                                                                          \
  }
#define G_STAGE_B(BUF, NH, KT)                                                 \
  {                                                                            \
    _Pragma("unroll") for (int i = 0; i < 2; ++i) {                            \
      int c = i * 8 + wid;                                                     \
      int rb = ((c >> 2) << 6) + (NH) * 32 + ((c & 3) << 3);                   \
      int r = rb + srow8;                                                      \
      __builtin_amdgcn_global_load_lds(                                        \
          (as1_uint*)(Bblk + (size_t)r * K + (KT) * 64 +                       \
                      ((schk ^ (r & 7)) << 3)),                                \
          (as3_uint*)(&Bs[BUF][rb * 64]), 16, 0, 0);                           \
    }                                                                          \
  }
#define LDA(BUF, MI, KK)                                                       \
  (*reinterpret_cast<const bf16x8*>(                                           \
      &As[BUF][(wr * 128 + (MI) * 16 + lr) * 64 +                              \
               ((((KK) * 4 + lg) ^ axr) << 3)]))
#define LDB(BUF, NI, KK)                                                       \
  (*reinterpret_cast<const bf16x8*>(                                           \
      &Bs[BUF][(wc * 64 + (NI) * 16 + lr) * 64 +                               \
               ((((KK) * 4 + lg) ^ axr) << 3)]))
#define PHASE_SYNC_IN()                                                        \
  asm volatile("" ::: "memory");                                               \
  __builtin_amdgcn_s_barrier();                                                \
  asm volatile("s_waitcnt lgkmcnt(0)" ::: "memory");                           \
  __builtin_amdgcn_sched_barrier(0);                                           \
  __builtin_amdgcn_s_setprio(1);
#define PHASE_SYNC_OUT()                                                       \
  __builtin_amdgcn_s_setprio(0);                                               \
  __builtin_amdgcn_s_barrier();                                                \
  asm volatile("" ::: "memory");

  f32x4 acc[8][4] = {};
  bf16x8 af[4][2], bfr[4][2];

  // ---- prologue: tile0 full (Am0,Bn0,Am1,Bn1), tile1 Am0,Bn0 = 12 loads ----
  G_STAGE_A(0, 0, 0);
  G_STAGE_B(0, 0, 0);
  G_STAGE_A(0, 1, 0);
  G_STAGE_B(0, 1, 0);
  if (NT > 1) {
    G_STAGE_A(1, 0, 1);
    G_STAGE_B(1, 0, 1);
  }
  asm volatile("s_waitcnt vmcnt(4)" ::: "memory");  // tile 0 landed
  __builtin_amdgcn_s_barrier();
  asm volatile("" ::: "memory");

  for (int t = 0; t < NT; ++t) {
    int cur = t & 1, nxt = cur ^ 1;
    int s1 = (t + 1 < NT) ? t + 1 : 0;
    int s2 = (t + 2 < NT) ? t + 2 : t + 2 - NT;

    // ===== p0: reads A{m0}(8) + B{n0}(4); stage A{m1}(s1)->nxt =====
#pragma unroll
    for (int mi = 0; mi < 4; ++mi)
#pragma unroll
      for (int kk = 0; kk < 2; ++kk) af[mi][kk] = LDA(cur, mi, kk);
#pragma unroll
    for (int ni = 0; ni < 2; ++ni)
#pragma unroll
      for (int kk = 0; kk < 2; ++kk) bfr[ni][kk] = LDB(cur, ni, kk);
    G_STAGE_A(nxt, 1, s1);
    PHASE_SYNC_IN();
#pragma unroll
    for (int mi = 0; mi < 4; ++mi)
#pragma unroll
      for (int ni = 0; ni < 2; ++ni)
#pragma unroll
        for (int kk = 0; kk < 2; ++kk)
          acc[mi][ni] = __builtin_amdgcn_mfma_f32_16x16x32_bf16(
              af[mi][kk], bfr[ni][kk], acc[mi][ni], 0, 0, 0);
    PHASE_SYNC_OUT();

    // ===== p1: reads B{n1}(4); stage B{n1}(s1)->nxt =====
#pragma unroll
    for (int ni = 2; ni < 4; ++ni)
#pragma unroll
      for (int kk = 0; kk < 2; ++kk) bfr[ni][kk] = LDB(cur, ni, kk);
    G_STAGE_B(nxt, 1, s1);
    PHASE_SYNC_IN();
#pragma unroll
    for (int mi = 0; mi < 4; ++mi)
#pragma unroll
      for (int ni = 2; ni < 4; ++ni)
#pragma unroll
        for (int kk = 0; kk < 2; ++kk)
          acc[mi][ni] = __builtin_amdgcn_mfma_f32_16x16x32_bf16(
              af[mi][kk], bfr[ni][kk], acc[mi][ni], 0, 0, 0);
    PHASE_SYNC_OUT();

    // ===== p2: reads A{m1}(8); stage A{m0}(s2)->cur =====
#pragma unroll
    for (int mi = 0; mi < 4; ++mi)
#pragma unroll
      for (int kk = 0; kk < 2; ++kk) af[mi][kk] = LDA(cur, 4 + mi, kk);
    G_STAGE_A(cur, 0, s2);
    PHASE_SYNC_IN();
#pragma unroll
    for (int mi = 0; mi < 4; ++mi)
#pragma unroll
      for (int ni = 0; ni < 2; ++ni)
#pragma unroll
        for (int kk = 0; kk < 2; ++kk)
          acc[4 + mi][ni] = __builtin_amdgcn_mfma_f32_16x16x32_bf16(
              af[mi][kk], bfr[ni][kk], acc[4 + mi][ni], 0, 0, 0);
    PHASE_SYNC_OUT();

    // ===== p3: no reads; stage B{n0}(s2)->cur; vmcnt(4) before end barrier ==
    G_STAGE_B(cur, 0, s2);
    asm volatile("" ::: "memory");
    __builtin_amdgcn_s_barrier();
    __builtin_amdgcn_s_setprio(1);
#pragma unroll
    for (int mi = 0; mi < 4; ++mi)
#pragma unroll
      for (int ni = 2; ni < 4; ++ni)
#pragma unroll
        for (int kk = 0; kk < 2; ++kk)
          acc[4 + mi][ni] = __builtin_amdgcn_mfma_f32_16x16x32_bf16(
              af[mi][kk], bfr[ni][kk], acc[4 + mi][ni], 0, 0, 0);
    __builtin_amdgcn_s_setprio(0);
    asm volatile("s_waitcnt vmcnt(4)" ::: "memory");  // tile t+1 landed
    __builtin_amdgcn_s_barrier();
    asm volatile("" ::: "memory");
  }

  // ---- epilogue: C write (proven layout: row via lg*4+j, col via lr) ----
#pragma unroll
  for (int mi = 0; mi < 8; ++mi) {
    int row = bm * 256 + wr * 128 + mi * 16 + lg * 4;
#pragma unroll
    for (int ni = 0; ni < 4; ++ni) {
      int col = bn * 256 + wc * 64 + ni * 16 + lr;
#pragma unroll
      for (int j = 0; j < 4; ++j) {
        if (F32OUT)
          ((float*)Cout)[(size_t)(row + j) * N + col] = acc[mi][ni][j];
        else
          ((unsigned short*)Cout)[(size_t)(row + j) * N + col] = f2bf(acc[mi][ni][j]);
      }
    }
  }
#undef G_STAGE_A
#undef G_STAGE_B
#undef LDA
#undef LDB
#undef PHASE_SYNC_IN
#undef PHASE_SYNC_OUT
}

// ---------------------------------------------------------------------------
// 4. Flash attention, swapped-operand form (unchanged from measured R5).
// ---------------------------------------------------------------------------
__global__ __launch_bounds__(256) void attn_kernel(
    const unsigned short* __restrict__ qkv, const float* __restrict__ bias,
    unsigned short* __restrict__ aout) {
  int phys = blockIdx.x;
  int id = (phys & 7) * 128 + (phys >> 3);  // bijective: 1024 = 8*128
  int b = id & 7, qt = (id >> 3) & 7, h = id >> 6;
  int tid = threadIdx.x, wid = tid >> 6, lane = tid & 63;
  int lg = lane >> 4, lr = lane & 15;

  __shared__ unsigned short Ks[2][64 * 64];   // [kv][d] linear, XOR-swizzled
  __shared__ unsigned short Vt[2][64 * 72];   // [d][kv] transposed, dbuf
  __shared__ unsigned short Ps[4][32 * 72];   // per-wave P [q][kv]

  const unsigned short* qbase = qkv + (size_t)(b * SEQ) * QKV3 + h * 64;
  const unsigned short* kbase = qbase + INNER;
  const unsigned short* vbase = qbase + 2 * INNER;
  const float* biash = bias + (size_t)h * SEQ * SEQ;

  int q0 = qt * 128 + wid * 32;

  bf16x8 qf[2][2];
#pragma unroll
  for (int mi = 0; mi < 2; ++mi)
#pragma unroll
    for (int kk = 0; kk < 2; ++kk)
      qf[mi][kk] = *reinterpret_cast<const bf16x8*>(
          qbase + (size_t)(q0 + mi * 16 + lr) * QKV3 + kk * 32 + lg * 8);

  const float* brow[2];
#pragma unroll
  for (int mi = 0; mi < 2; ++mi)
    brow[mi] = biash + (size_t)(q0 + mi * 16 + lr) * SEQ;

  int vrow = tid & 63;
  int vchunk = tid >> 6;
  int krow_in = lane >> 3;
  int kchunk = lane & 7;
  int kxor = lr & 7;

#pragma unroll
  for (int i = 0; i < 2; ++i) {
    int r = wid * 16 + i * 8 + krow_in;
    __builtin_amdgcn_global_load_lds(
        (as1_uint*)(kbase + (size_t)r * QKV3 + (kchunk ^ (r & 7)) * 8),
        (as3_uint*)(&Ks[0][(wid * 16 + i * 8) * 64]), 16, 0, 0);
  }
  u16x8 vreg[2];
#pragma unroll
  for (int it = 0; it < 2; ++it)
    vreg[it] = *reinterpret_cast<const u16x8*>(
        vbase + (size_t)vrow * QKV3 + (vchunk + it * 4) * 8);

  f32x4 oacc[2][4] = {};
  float mrun[2] = {-1e30f, -1e30f}, lrun[2] = {0.f, 0.f};

#define ATTN_STEP(TT, BUF, PREFETCH)                                           \
  {                                                                            \
    _Pragma("unroll") for (int it = 0; it < 2; ++it)                           \
        _Pragma("unroll") for (int i = 0; i < 8; ++i)                          \
            Vt[BUF][((vchunk + it * 4) * 8 + i) * 72 + vrow] = vreg[it][i];    \
    __syncthreads();                                                           \
    if (PREFETCH) {                                                            \
      _Pragma("unroll") for (int i = 0; i < 2; ++i) {                          \
        int r = wid * 16 + i * 8 + krow_in;                                    \
        __builtin_amdgcn_global_load_lds(                                      \
            (as1_uint*)(kbase + (size_t)(((TT) + 1) * 64 + r) * QKV3 +         \
                        (kchunk ^ (r & 7)) * 8),                               \
            (as3_uint*)(&Ks[1 - (BUF)][(wid * 16 + i * 8) * 64]), 16, 0, 0);   \
      }                                                                        \
      _Pragma("unroll") for (int it = 0; it < 2; ++it)                         \
          vreg[it] = *reinterpret_cast<const u16x8*>(                          \
              vbase + (size_t)(((TT) + 1) * 64 + vrow) * QKV3 +                \
              (vchunk + it * 4) * 8);                                          \
    }                                                                          \
    f32x4 bv[2][4];                                                            \
    _Pragma("unroll") for (int mi = 0; mi < 2; ++mi)                           \
        _Pragma("unroll") for (int kb = 0; kb < 4; ++kb)                       \
            bv[mi][kb] = *reinterpret_cast<const f32x4*>(                      \
                brow[mi] + (TT) * 64 + kb * 16 + lg * 4);                      \
    f32x4 s[2][4] = {};                                                        \
    const unsigned short* ksb = Ks[BUF];                                       \
    __builtin_amdgcn_s_setprio(1);                                             \
    _Pragma("unroll") for (int kb = 0; kb < 4; ++kb) {                         \
      int rowb = (kb * 16 + lr) * 64;                                          \
      bf16x8 k0 = *reinterpret_cast<const bf16x8*>(                            \
          ksb + rowb + ((lg ^ kxor) << 3));                                    \
      bf16x8 k1 = *reinterpret_cast<const bf16x8*>(                            \
          ksb + rowb + (((4 + lg) ^ kxor) << 3));                              \
      _Pragma("unroll") for (int mi = 0; mi < 2; ++mi) {                       \
        s[mi][kb] = __builtin_amdgcn_mfma_f32_16x16x32_bf16(                   \
            k0, qf[mi][0], s[mi][kb], 0, 0, 0);                                \
        s[mi][kb] = __builtin_amdgcn_mfma_f32_16x16x32_bf16(                   \
            k1, qf[mi][1], s[mi][kb], 0, 0, 0);                                \
      }                                                                        \
    }                                                                          \
    __builtin_amdgcn_s_setprio(0);                                             \
    _Pragma("unroll") for (int mi = 0; mi < 2; ++mi)                           \
        _Pragma("unroll") for (int kb = 0; kb < 4; ++kb)                       \
            _Pragma("unroll") for (int j = 0; j < 4; ++j)                      \
                s[mi][kb][j] += bv[mi][kb][j];                                 \
    float alpha[2];                                                            \
    _Pragma("unroll") for (int mi = 0; mi < 2; ++mi) {                         \
      float t0 = fmaxf(fmaxf(s[mi][0][0], s[mi][0][1]),                        \
                       fmaxf(s[mi][0][2], s[mi][0][3]));                       \
      float t1 = fmaxf(fmaxf(s[mi][1][0], s[mi][1][1]),                        \
                       fmaxf(s[mi][1][2], s[mi][1][3]));                       \
      float t2 = fmaxf(fmaxf(s[mi][2][0], s[mi][2][1]),                        \
                       fmaxf(s[mi][2][2], s[mi][2][3]));                       \
      float t3 = fmaxf(fmaxf(s[mi][3][0], s[mi][3][1]),                        \
                       fmaxf(s[mi][3][2], s[mi][3][3]));                       \
      float rm = fmaxf(fmaxf(t0, t1), fmaxf(t2, t3));                          \
      rm = fmaxf(rm, __shfl_xor(rm, 16, 64));                                  \
      rm = fmaxf(rm, __shfl_xor(rm, 32, 64));                                  \
      float mnew = fmaxf(mrun[mi], rm);                                        \
      alpha[mi] = __expf(mrun[mi] - mnew);                                     \
      mrun[mi] = mnew;                                                         \
      float ls = 0.f;                                                          \
      _Pragma("unroll") for (int kb = 0; kb < 4; ++kb) {                       \
        float e0 = __expf(s[mi][kb][0] - mnew);                                \
        float e1 = __expf(s[mi][kb][1] - mnew);                                \
        float e2 = __expf(s[mi][kb][2] - mnew);                                \
        float e3 = __expf(s[mi][kb][3] - mnew);                                \
        s[mi][kb][0] = e0; s[mi][kb][1] = e1;                                  \
        s[mi][kb][2] = e2; s[mi][kb][3] = e3;                                  \
        ls += (e0 + e1) + (e2 + e3);                                           \
      }                                                                        \
      ls += __shfl_xor(ls, 16, 64);                                            \
      ls += __shfl_xor(ls, 32, 64);                                            \
      lrun[mi] = lrun[mi] * alpha[mi] + ls;                                    \
    }                                                                          \
    _Pragma("unroll") for (int mi = 0; mi < 2; ++mi)                           \
        _Pragma("unroll") for (int kb = 0; kb < 4; ++kb) {                     \
      u16x4 pk;                                                                \
      pk[0] = f2bf_fast(s[mi][kb][0]);                                         \
      pk[1] = f2bf_fast(s[mi][kb][1]);                                         \
      pk[2] = f2bf_fast(s[mi][kb][2]);                                         \
      pk[3] = f2bf_fast(s[mi][kb][3]);                                         \
      *reinterpret_cast<u16x4*>(                                               \
          &Ps[wid][(mi * 16 + lr) * 72 + kb * 16 + lg * 4]) = pk;              \
    }                                                                          \
    asm volatile("s_waitcnt lgkmcnt(0)" ::: "memory");                         \
    __builtin_amdgcn_sched_barrier(0);                                         \
    _Pragma("unroll") for (int mi = 0; mi < 2; ++mi)                           \
        _Pragma("unroll") for (int db = 0; db < 4; ++db)                       \
            _Pragma("unroll") for (int j = 0; j < 4; ++j)                      \
                oacc[mi][db][j] *= alpha[mi];                                  \
    __builtin_amdgcn_s_setprio(1);                                             \
    _Pragma("unroll") for (int k2 = 0; k2 < 2; ++k2) {                         \
      bf16x8 va[4], pb[2];                                                     \
      _Pragma("unroll") for (int db = 0; db < 4; ++db)                         \
          va[db] = *reinterpret_cast<const bf16x8*>(                           \
              &Vt[BUF][(db * 16 + lr) * 72 + k2 * 32 + lg * 8]);               \
      _Pragma("unroll") for (int mi = 0; mi < 2; ++mi)                         \
          pb[mi] = *reinterpret_cast<const bf16x8*>(                           \
              &Ps[wid][(mi * 16 + lr) * 72 + k2 * 32 + lg * 8]);               \
      _Pragma("unroll") for (int mi = 0; mi < 2; ++mi)                         \
          _Pragma("unroll") for (int db = 0; db < 4; ++db)                     \
              oacc[mi][db] = __builtin_amdgcn_mfma_f32_16x16x32_bf16(          \
                  va[db], pb[mi], oacc[mi][db], 0, 0, 0);                      \
    }                                                                          \
    __builtin_amdgcn_s_setprio(0);                                             \
  }

  for (int t = 0; t < 16; t += 2) {
    ATTN_STEP(t, 0, true);
    ATTN_STEP(t + 1, 1, (t + 1) < 15);
  }
#undef ATTN_STEP

#pragma unroll
  for (int mi = 0; mi < 2; ++mi) {
    float inv = 1.0f / lrun[mi];
    size_t row = (size_t)(b * SEQ + q0 + mi * 16 + lr) * INNER + h * 64;
#pragma unroll
    for (int db = 0; db < 4; ++db) {
      u16x4 o;
      o[0] = f2bf_fast(oacc[mi][db][0] * inv);
      o[1] = f2bf_fast(oacc[mi][db][1] * inv);
      o[2] = f2bf_fast(oacc[mi][db][2] * inv);
      o[3] = f2bf_fast(oacc[mi][db][3] * inv);
      *reinterpret_cast<u16x4*>(&aout[row + db * 16 + lg * 4]) = o;
    }
  }
}

// ---------------------------------------------------------------------------
extern "C" void kernel_launch(void* const* d_in, const int* in_sizes, int n_in,
                              void* d_out, int out_size, void* d_ws, size_t ws_size,
                              hipStream_t stream) {
  const float* x = (const float*)d_in[0];
  const float* gamma = (const float*)d_in[1];
  const float* beta = (const float*)d_in[2];
  const float* w_qkv = (const float*)d_in[3];
  const float* w_out = (const float*)d_in[4];
  const float* bias = (const float*)d_in[5];

  char* ws = (char*)d_ws;
  unsigned short* xn = (unsigned short*)(ws);
  unsigned short* wqkv_t = (unsigned short*)(ws + 16777216);
  unsigned short* wout_t = (unsigned short*)(ws + 23068672);
  unsigned short* qkvb = (unsigned short*)(ws + 25165824);
  unsigned short* aout = (unsigned short*)(ws + 75497472);

  ln_bf16_kernel<<<BATCH * SEQ, 256, 0, stream>>>(x, gamma, beta, xn);
  transpose_cvt<<<dim3(QKV3 / 32, DIM / 32), dim3(32, 8), 0, stream>>>(
      w_qkv, wqkv_t, DIM, QKV3, INNER);
  transpose_cvt<<<dim3(DIM / 32, INNER / 32), dim3(32, 8), 0, stream>>>(
      w_out, wout_t, INNER, DIM, 0);
  gemm8<false><<<(BATCH * SEQ / 256) * (QKV3 / 256), 512, 0, stream>>>(
      xn, wqkv_t, (void*)qkvb, BATCH * SEQ, QKV3, DIM);
  attn_kernel<<<BATCH * HEADS * (SEQ / 128), 256, 0, stream>>>(qkvb, bias, aout);
  gemm8<true><<<(BATCH * SEQ / 256) * (DIM / 256), 512, 0, stream>>>(
      aout, wout_t, d_out, BATCH * SEQ, DIM, INNER);
}

// Round 9
// 341.307 us; speedup vs baseline: 1.0046x; 1.0046x over previous
//
#include <hip/hip_runtime.h>

// ---------------------------------------------------------------------------
// BiasedAttention fused pipeline (MI355X / gfx950) — R9 (= R7 resubmitted)
//   GEMMs: ring-3 counted-vmcnt (measured best, R5: non-attn ~213us).
//   attn: softmax de-serialized — T13 defer-max (THR=8, wave-uniform skip of
//   max-shuffles/rescale/alpha-exp) + deferred l-reduction (per-lane partial
//   sums, single epilogue group-reduce). Steady-state tile has ZERO cross-lane
//   ops on the LDS pipe.
// Workspace layout (bytes):
//   xn      bf16  8192*1024*2  = 16777216   @ 0
//   wqkv_t  bf16  3072*1024*2  =  6291456   @ 16777216
//   wout_t  bf16  1024*1024*2  =  2097152   @ 23068672
//   qkv     bf16  8192*3072*2  = 50331648   @ 25165824
//   aout    bf16  8192*1024*2  = 16777216   @ 75497472
// ---------------------------------------------------------------------------

#define DIM    1024
#define HEADS  16
#define DHEAD  64
#define INNER  1024
#define SEQ    1024
#define BATCH  8
#define QKV3   3072

typedef __bf16 bf16x8 __attribute__((ext_vector_type(8)));
typedef float f32x4 __attribute__((ext_vector_type(4)));
typedef unsigned short u16x8 __attribute__((ext_vector_type(8)));
typedef unsigned short u16x4 __attribute__((ext_vector_type(4)));

typedef __attribute__((address_space(1))) const unsigned int as1_uint;
typedef __attribute__((address_space(3))) unsigned int as3_uint;

static __device__ inline unsigned short f2bf(float f) {
  unsigned int u = __float_as_uint(f);
  u = (u + 0x7FFFu + ((u >> 16) & 1u)) >> 16;  // RNE
  return (unsigned short)u;
}
static __device__ inline unsigned short f2bf_fast(float f) {
  __bf16 h = (__bf16)f;
  return __builtin_bit_cast(unsigned short, h);
}

// ---------------------------------------------------------------------------
// 1. LayerNorm fp32 -> bf16
// ---------------------------------------------------------------------------
__global__ __launch_bounds__(256) void ln_bf16_kernel(
    const float* __restrict__ x, const float* __restrict__ gamma,
    const float* __restrict__ beta, unsigned short* __restrict__ xn) {
  int row = blockIdx.x;
  int tid = threadIdx.x;
  const float4* xr = reinterpret_cast<const float4*>(x + (size_t)row * DIM);
  float4 v = xr[tid];
  float s = v.x + v.y + v.z + v.w;
  float s2 = v.x * v.x + v.y * v.y + v.z * v.z + v.w * v.w;
#pragma unroll
  for (int m = 32; m; m >>= 1) {
    s += __shfl_xor(s, m, 64);
    s2 += __shfl_xor(s2, m, 64);
  }
  __shared__ float red[2][4];
  int wid = tid >> 6, lane = tid & 63;
  if (lane == 0) { red[0][wid] = s; red[1][wid] = s2; }
  __syncthreads();
  s = red[0][0] + red[0][1] + red[0][2] + red[0][3];
  s2 = red[1][0] + red[1][1] + red[1][2] + red[1][3];
  float mu = s * (1.0f / DIM);
  float var = s2 * (1.0f / DIM) - mu * mu;
  float rstd = rsqrtf(var + 1e-5f);
  float4 g = reinterpret_cast<const float4*>(gamma)[tid];
  float4 b = reinterpret_cast<const float4*>(beta)[tid];
  u16x4 o;
  o[0] = f2bf((v.x - mu) * rstd * g.x + b.x);
  o[1] = f2bf((v.y - mu) * rstd * g.y + b.y);
  o[2] = f2bf((v.z - mu) * rstd * g.z + b.z);
  o[3] = f2bf((v.w - mu) * rstd * g.w + b.w);
  *reinterpret_cast<u16x4*>(xn + (size_t)row * DIM + tid * 4) = o;
}

// ---------------------------------------------------------------------------
// 2. Transpose + fp32->bf16:  W[R][C] -> Wt[C][R]; rows < scale_rows get *0.125
// ---------------------------------------------------------------------------
__global__ __launch_bounds__(256) void transpose_cvt(
    const float* __restrict__ W, unsigned short* __restrict__ Wt, int R, int C,
    int scale_rows) {
  __shared__ float tb[32][33];
  int c0 = blockIdx.x * 32, r0 = blockIdx.y * 32;
  int tx = threadIdx.x, ty = threadIdx.y;  // (32, 8)
#pragma unroll
  for (int i = 0; i < 4; ++i)
    tb[ty + i * 8][tx] = W[(size_t)(r0 + ty + i * 8) * C + c0 + tx];
  __syncthreads();
#pragma unroll
  for (int i = 0; i < 4; ++i) {
    int orow = c0 + ty + i * 8;
    float v = tb[tx][ty + i * 8];
    if (orow < scale_rows) v *= 0.125f;
    Wt[(size_t)orow * R + r0 + tx] = f2bf(v);
  }
}

// ---------------------------------------------------------------------------
// 3. GEMM  C[M,N] = A[M,K] @ Bt[N,K]^T   (bf16 in, fp32 acc) — ring-3 (R5)
// ---------------------------------------------------------------------------
template <bool F32OUT>
__global__ __launch_bounds__(256) void gemm_ring(
    const unsigned short* __restrict__ A, const unsigned short* __restrict__ Bt,
    void* __restrict__ Cout, int M, int N, int K) {
  __shared__ unsigned short As[3][128 * 32];
  __shared__ unsigned short Bs[3][128 * 32];
  int nb = N >> 7;
  int nwg = (M >> 7) * nb;
  int cpx = nwg >> 3;
  int phys = blockIdx.x;
  int swz = (phys & 7) * cpx + (phys >> 3);  // bijective (nwg % 8 == 0)
  int bm = swz / nb, bn = swz % nb;
  int tid = threadIdx.x, wid = tid >> 6, lane = tid & 63;
  int wr = wid >> 1, wc = wid & 1;
  int lg = lane >> 4, lr = lane & 15;
  const unsigned short* Ablk = A + (size_t)(bm * 128) * K;
  const unsigned short* Bblk = Bt + (size_t)(bn * 128) * K;

  int sr0 = wid * 32 + (lane >> 2);
  int sc = lane & 3;
  int r0 = sr0, r1 = sr0 + 16;
  size_t aoff0 = (size_t)r0 * K + (sc ^ ((r0 >> 1) & 3)) * 8;
  size_t aoff1 = (size_t)r1 * K + (sc ^ ((r1 >> 1) & 3)) * 8;
  int ldst0 = (wid * 32) * 32;
  int ldst1 = (wid * 32 + 16) * 32;
  int NT = K >> 5;

  int rdc = (lg ^ ((lr >> 1) & 3)) * 8;

  f32x4 acc[4][4] = {};

#pragma unroll
  for (int t2 = 0; t2 < 2; ++t2) {
    __builtin_amdgcn_global_load_lds((as1_uint*)(Ablk + aoff0 + t2 * 32),
                                     (as3_uint*)(&As[t2][ldst0]), 16, 0, 0);
    __builtin_amdgcn_global_load_lds((as1_uint*)(Bblk + aoff0 + t2 * 32),
                                     (as3_uint*)(&Bs[t2][ldst0]), 16, 0, 0);
    __builtin_amdgcn_global_load_lds((as1_uint*)(Ablk + aoff1 + t2 * 32),
                                     (as3_uint*)(&As[t2][ldst1]), 16, 0, 0);
    __builtin_amdgcn_global_load_lds((as1_uint*)(Bblk + aoff1 + t2 * 32),
                                     (as3_uint*)(&Bs[t2][ldst1]), 16, 0, 0);
  }
  asm volatile("s_waitcnt vmcnt(4)" ::: "memory");  // tile 0 landed
  __builtin_amdgcn_s_barrier();
  asm volatile("" ::: "memory");

  int s0 = 0;
  for (int kt = 0; kt < NT; ++kt) {
    const unsigned short* as = As[s0];
    const unsigned short* bs = Bs[s0];
    bf16x8 a[4], b[4];
#pragma unroll
    for (int mi = 0; mi < 4; ++mi)
      a[mi] = *reinterpret_cast<const bf16x8*>(
          as + (wr * 64 + mi * 16 + lr) * 32 + rdc);
#pragma unroll
    for (int ni = 0; ni < 4; ++ni)
      b[ni] = *reinterpret_cast<const bf16x8*>(
          bs + (wc * 64 + ni * 16 + lr) * 32 + rdc);

    int st = kt + 2; if (st >= NT) st -= NT;
    int ss = s0 + 2; if (ss >= 3) ss -= 3;
    __builtin_amdgcn_global_load_lds((as1_uint*)(Ablk + aoff0 + st * 32),
                                     (as3_uint*)(&As[ss][ldst0]), 16, 0, 0);
    __builtin_amdgcn_global_load_lds((as1_uint*)(Bblk + aoff0 + st * 32),
                                     (as3_uint*)(&Bs[ss][ldst0]), 16, 0, 0);
    __builtin_amdgcn_global_load_lds((as1_uint*)(Ablk + aoff1 + st * 32),
                                     (as3_uint*)(&As[ss][ldst1]), 16, 0, 0);
    __builtin_amdgcn_global_load_lds((as1_uint*)(Bblk + aoff1 + st * 32),
                                     (as3_uint*)(&Bs[ss][ldst1]), 16, 0, 0);

    __builtin_amdgcn_s_setprio(1);
#pragma unroll
    for (int mi = 0; mi < 4; ++mi)
#pragma unroll
      for (int ni = 0; ni < 4; ++ni)
        acc[mi][ni] = __builtin_amdgcn_mfma_f32_16x16x32_bf16(
            a[mi], b[ni], acc[mi][ni], 0, 0, 0);
    __builtin_amdgcn_s_setprio(0);

    asm volatile("s_waitcnt vmcnt(4)" ::: "memory");
    __builtin_amdgcn_s_barrier();
    asm volatile("" ::: "memory");
    s0 = (s0 == 2) ? 0 : s0 + 1;
  }

#pragma unroll
  for (int mi = 0; mi < 4; ++mi) {
    int row = bm * 128 + wr * 64 + mi * 16 + lg * 4;
#pragma unroll
    for (int ni = 0; ni < 4; ++ni) {
      int col = bn * 128 + wc * 64 + ni * 16 + lr;
#pragma unroll
      for (int j = 0; j < 4; ++j) {
        if (F32OUT)
          ((float*)Cout)[(size_t)(row + j) * N + col] = acc[mi][ni][j];
        else
          ((unsigned short*)Cout)[(size_t)(row + j) * N + col] = f2bf(acc[mi][ni][j]);
      }
    }
  }
}

// ---------------------------------------------------------------------------
// 4. Flash attention, swapped-operand form + defer-max + deferred l-reduce.
//    Lanes {l, l^16, l^32, l^48} share one q-row (col=lr), so __any() over
//    the wave of the per-lane 16-max is an exact row-level skip test.
//    Steady state (no rescale): zero cross-lane ops per tile.
// ---------------------------------------------------------------------------
__global__ __launch_bounds__(256) void attn_kernel(
    const unsigned short* __restrict__ qkv, const float* __restrict__ bias,
    unsigned short* __restrict__ aout) {
  int phys = blockIdx.x;
  int id = (phys & 7) * 128 + (phys >> 3);  // bijective: 1024 = 8*128
  int b = id & 7, qt = (id >> 3) & 7, h = id >> 6;
  int tid = threadIdx.x, wid = tid >> 6, lane = tid & 63;
  int lg = lane >> 4, lr = lane & 15;

  __shared__ unsigned short Ks[2][64 * 64];   // [kv][d] linear, XOR-swizzled
  __shared__ unsigned short Vt[2][64 * 72];   // [d][kv] transposed, dbuf
  __shared__ unsigned short Ps[4][32 * 72];   // per-wave P [q][kv]

  const unsigned short* qbase = qkv + (size_t)(b * SEQ) * QKV3 + h * 64;
  const unsigned short* kbase = qbase + INNER;
  const unsigned short* vbase = qbase + 2 * INNER;
  const float* biash = bias + (size_t)h * SEQ * SEQ;

  int q0 = qt * 128 + wid * 32;

  bf16x8 qf[2][2];
#pragma unroll
  for (int mi = 0; mi < 2; ++mi)
#pragma unroll
    for (int kk = 0; kk < 2; ++kk)
      qf[mi][kk] = *reinterpret_cast<const bf16x8*>(
          qbase + (size_t)(q0 + mi * 16 + lr) * QKV3 + kk * 32 + lg * 8);

  const float* brow[2];
#pragma unroll
  for (int mi = 0; mi < 2; ++mi)
    brow[mi] = biash + (size_t)(q0 + mi * 16 + lr) * SEQ;

  int vrow = tid & 63;
  int vchunk = tid >> 6;
  int krow_in = lane >> 3;
  int kchunk = lane & 7;
  int kxor = lr & 7;

#pragma unroll
  for (int i = 0; i < 2; ++i) {
    int r = wid * 16 + i * 8 + krow_in;
    __builtin_amdgcn_global_load_lds(
        (as1_uint*)(kbase + (size_t)r * QKV3 + (kchunk ^ (r & 7)) * 8),
        (as3_uint*)(&Ks[0][(wid * 16 + i * 8) * 64]), 16, 0, 0);
  }
  u16x8 vreg[2];
#pragma unroll
  for (int it = 0; it < 2; ++it)
    vreg[it] = *reinterpret_cast<const u16x8*>(
        vbase + (size_t)vrow * QKV3 + (vchunk + it * 4) * 8);

  f32x4 oacc[2][4] = {};
  float mrun[2] = {-1e30f, -1e30f};
  float lsum[2] = {0.f, 0.f};   // per-lane partial; group-reduced in epilogue

#define ATTN_STEP(TT, BUF, PREFETCH)                                           \
  {                                                                            \
    _Pragma("unroll") for (int it = 0; it < 2; ++it)                           \
        _Pragma("unroll") for (int i = 0; i < 8; ++i)                          \
            Vt[BUF][((vchunk + it * 4) * 8 + i) * 72 + vrow] = vreg[it][i];    \
    __syncthreads();                                                           \
    if (PREFETCH) {                                                            \
      _Pragma("unroll") for (int i = 0; i < 2; ++i) {                          \
        int r = wid * 16 + i * 8 + krow_in;                                    \
        __builtin_amdgcn_global_load_lds(                                      \
            (as1_uint*)(kbase + (size_t)(((TT) + 1) * 64 + r) * QKV3 +         \
                        (kchunk ^ (r & 7)) * 8),                               \
            (as3_uint*)(&Ks[1 - (BUF)][(wid * 16 + i * 8) * 64]), 16, 0, 0);   \
      }                                                                        \
      _Pragma("unroll") for (int it = 0; it < 2; ++it)                         \
          vreg[it] = *reinterpret_cast<const u16x8*>(                          \
              vbase + (size_t)(((TT) + 1) * 64 + vrow) * QKV3 +                \
              (vchunk + it * 4) * 8);                                          \
    }                                                                          \
    f32x4 bv[2][4];                                                            \
    _Pragma("unroll") for (int mi = 0; mi < 2; ++mi)                           \
        _Pragma("unroll") for (int kb = 0; kb < 4; ++kb)                       \
            bv[mi][kb] = *reinterpret_cast<const f32x4*>(                      \
                brow[mi] + (TT) * 64 + kb * 16 + lg * 4);                      \
    f32x4 s[2][4] = {};                                                        \
    const unsigned short* ksb = Ks[BUF];                                       \
    __builtin_amdgcn_s_setprio(1);                                             \
    _Pragma("unroll") for (int kb = 0; kb < 4; ++kb) {                         \
      int rowb = (kb * 16 + lr) * 64;                                          \
      bf16x8 k0 = *reinterpret_cast<const bf16x8*>(                            \
          ksb + rowb + ((lg ^ kxor) << 3));                                    \
      bf16x8 k1 = *reinterpret_cast<const bf16x8*>(                            \
          ksb + rowb + (((4 + lg) ^ kxor) << 3));                              \
      _Pragma("unroll") for (int mi = 0; mi < 2; ++mi) {                       \
        s[mi][kb] = __builtin_amdgcn_mfma_f32_16x16x32_bf16(                   \
            k0, qf[mi][0], s[mi][kb], 0, 0, 0);                                \
        s[mi][kb] = __builtin_amdgcn_mfma_f32_16x16x32_bf16(                   \
            k1, qf[mi][1], s[mi][kb], 0, 0, 0);                                \
      }                                                                        \
    }                                                                          \
    __builtin_amdgcn_s_setprio(0);                                             \
    _Pragma("unroll") for (int mi = 0; mi < 2; ++mi)                           \
        _Pragma("unroll") for (int kb = 0; kb < 4; ++kb)                       \
            _Pragma("unroll") for (int j = 0; j < 4; ++j)                      \
                s[mi][kb][j] += bv[mi][kb][j];                                 \
    int need[2];                                                               \
    float alpha[2];                                                            \
    _Pragma("unroll") for (int mi = 0; mi < 2; ++mi) {                         \
      float t0 = fmaxf(fmaxf(s[mi][0][0], s[mi][0][1]),                        \
                       fmaxf(s[mi][0][2], s[mi][0][3]));                       \
      float t1 = fmaxf(fmaxf(s[mi][1][0], s[mi][1][1]),                        \
                       fmaxf(s[mi][1][2], s[mi][1][3]));                       \
      float t2 = fmaxf(fmaxf(s[mi][2][0], s[mi][2][1]),                        \
                       fmaxf(s[mi][2][2], s[mi][2][3]));                       \
      float t3 = fmaxf(fmaxf(s[mi][3][0], s[mi][3][1]),                        \
                       fmaxf(s[mi][3][2], s[mi][3][3]));                       \
      float rm = fmaxf(fmaxf(t0, t1), fmaxf(t2, t3));                          \
      need[mi] = __any(rm > mrun[mi] + 8.f);                                   \
      alpha[mi] = 1.f;                                                         \
      if (need[mi]) { /* wave-uniform */                                       \
        rm = fmaxf(rm, __shfl_xor(rm, 16, 64));                                \
        rm = fmaxf(rm, __shfl_xor(rm, 32, 64));                                \
        float mnew = fmaxf(mrun[mi], rm);                                      \
        alpha[mi] = __expf(mrun[mi] - mnew);                                   \
        mrun[mi] = mnew;                                                       \
      }                                                                        \
      float ls = 0.f;                                                          \
      _Pragma("unroll") for (int kb = 0; kb < 4; ++kb) {                       \
        float e0 = __expf(s[mi][kb][0] - mrun[mi]);                            \
        float e1 = __expf(s[mi][kb][1] - mrun[mi]);                            \
        float e2 = __expf(s[mi][kb][2] - mrun[mi]);                            \
        float e3 = __expf(s[mi][kb][3] - mrun[mi]);                            \
        s[mi][kb][0] = e0; s[mi][kb][1] = e1;                                  \
        s[mi][kb][2] = e2; s[mi][kb][3] = e3;                                  \
        ls += (e0 + e1) + (e2 + e3);                                           \
      }                                                                        \
      lsum[mi] = lsum[mi] * alpha[mi] + ls;                                    \
    }                                                                          \
    _Pragma("unroll") for (int mi = 0; mi < 2; ++mi)                           \
        _Pragma("unroll") for (int kb = 0; kb < 4; ++kb) {                     \
      u16x4 pk;                                                                \
      pk[0] = f2bf_fast(s[mi][kb][0]);                                         \
      pk[1] = f2bf_fast(s[mi][kb][1]);                                         \
      pk[2] = f2bf_fast(s[mi][kb][2]);                                         \
      pk[3] = f2bf_fast(s[mi][kb][3]);                                         \
      *reinterpret_cast<u16x4*>(                                               \
          &Ps[wid][(mi * 16 + lr) * 72 + kb * 16 + lg * 4]) = pk;              \
    }                                                                          \
    asm volatile("s_waitcnt lgkmcnt(0)" ::: "memory");                         \
    __builtin_amdgcn_sched_barrier(0);                                         \
    _Pragma("unroll") for (int mi = 0; mi < 2; ++mi)                           \
      if (need[mi]) { /* wave-uniform rescale */                               \
        _Pragma("unroll") for (int db = 0; db < 4; ++db)                       \
            _Pragma("unroll") for (int j = 0; j < 4; ++j)                      \
                oacc[mi][db][j] *= alpha[mi];                                  \
      }                                                                        \
    __builtin_amdgcn_s_setprio(1);                                             \
    _Pragma("unroll") for (int k2 = 0; k2 < 2; ++k2) {                         \
      bf16x8 va[4], pb[2];                                                     \
      _Pragma("unroll") for (int db = 0; db < 4; ++db)                         \
          va[db] = *reinterpret_cast<const bf16x8*>(                           \
              &Vt[BUF][(db * 16 + lr) * 72 + k2 * 32 + lg * 8]);               \
      _Pragma("unroll") for (int mi = 0; mi < 2; ++mi)                         \
          pb[mi] = *reinterpret_cast<const bf16x8*>(                           \
              &Ps[wid][(mi * 16 + lr) * 72 + k2 * 32 + lg * 8]);               \
      _Pragma("unroll") for (int mi = 0; mi < 2; ++mi)                         \
          _Pragma("unroll") for (int db = 0; db < 4; ++db)                     \
              oacc[mi][db] = __builtin_amdgcn_mfma_f32_16x16x32_bf16(          \
                  va[db], pb[mi], oacc[mi][db], 0, 0, 0);                      \
    }                                                                          \
    __builtin_amdgcn_s_setprio(0);                                             \
  }

  for (int t = 0; t < 16; t += 2) {
    ATTN_STEP(t, 0, true);
    ATTN_STEP(t + 1, 1, (t + 1) < 15);
  }
#undef ATTN_STEP

  // ---- epilogue: single group-reduce of lsum, then O / l -> aout bf16 ----
#pragma unroll
  for (int mi = 0; mi < 2; ++mi) {
    float l = lsum[mi];
    l += __shfl_xor(l, 16, 64);
    l += __shfl_xor(l, 32, 64);
    float inv = 1.0f / l;
    size_t row = (size_t)(b * SEQ + q0 + mi * 16 + lr) * INNER + h * 64;
#pragma unroll
    for (int db = 0; db < 4; ++db) {
      u16x4 o;
      o[0] = f2bf_fast(oacc[mi][db][0] * inv);
      o[1] = f2bf_fast(oacc[mi][db][1] * inv);
      o[2] = f2bf_fast(oacc[mi][db][2] * inv);
      o[3] = f2bf_fast(oacc[mi][db][3] * inv);
      *reinterpret_cast<u16x4*>(&aout[row + db * 16 + lg * 4]) = o;
    }
  }
}

// ---------------------------------------------------------------------------
extern "C" void kernel_launch(void* const* d_in, const int* in_sizes, int n_in,
                              void* d_out, int out_size, void* d_ws, size_t ws_size,
                              hipStream_t stream) {
  const float* x = (const float*)d_in[0];
  const float* gamma = (const float*)d_in[1];
  const float* beta = (const float*)d_in[2];
  const float* w_qkv = (const float*)d_in[3];
  const float* w_out = (const float*)d_in[4];
  const float* bias = (const float*)d_in[5];

  char* ws = (char*)d_ws;
  unsigned short* xn = (unsigned short*)(ws);
  unsigned short* wqkv_t = (unsigned short*)(ws + 16777216);
  unsigned short* wout_t = (unsigned short*)(ws + 23068672);
  unsigned short* qkvb = (unsigned short*)(ws + 25165824);
  unsigned short* aout = (unsigned short*)(ws + 75497472);

  ln_bf16_kernel<<<BATCH * SEQ, 256, 0, stream>>>(x, gamma, beta, xn);
  transpose_cvt<<<dim3(QKV3 / 32, DIM / 32), dim3(32, 8), 0, stream>>>(
      w_qkv, wqkv_t, DIM, QKV3, INNER);
  transpose_cvt<<<dim3(DIM / 32, INNER / 32), dim3(32, 8), 0, stream>>>(
      w_out, wout_t, INNER, DIM, 0);
  gemm_ring<false><<<(BATCH * SEQ / 128) * (QKV3 / 128), 256, 0, stream>>>(
      xn, wqkv_t, (void*)qkvb, BATCH * SEQ, QKV3, DIM);
  attn_kernel<<<BATCH * HEADS * (SEQ / 128), 256, 0, stream>>>(qkvb, bias, aout);
  gemm_ring<true><<<(BATCH * SEQ / 128) * (DIM / 128), 256, 0, stream>>>(
      aout, wout_t, d_out, BATCH * SEQ, DIM, INNER);
}